// Round 10
// baseline (1018.858 us; speedup 1.0000x reference)
//
#include <hip/hip_runtime.h>
#include <hip/hip_bf16.h>

// ---------------------------------------------------------------------------
// 2-layer GraphConv (DGL norm='both') + mean_nodes pool + linear classifier.
// N=80000, E=1.28M, D=H=64, C=5, G=512.
// R9->R10: wave-per-node gather replaced by EDGE-PARALLEL aggregation.
// Block = 64-node tile; its CSR edges are contiguous (~1024+-32, balanced).
// Threads stream edges: load packed word + 16B row chunk, 8x ds_add_f32 into
// LDS acc[64][65] (stride 65 kills bank clustering). No per-node serial
// chain at all (R9 post-mortem: agg was latency-serial per node, deg~16 =>
// ~2 loads in flight). The 64x64 fp32 sums in LDS are exactly an MFMA
// A-tile -> GEMM + relu/norm epilogue fused into the same block (safe now:
// unlike R8, the gather phase has no round serialization). col stores the
// full (dstLocal<<17|src) word; deg[], s1/s2 buffers, gemm dispatches gone.
// 6 dispatches total. CSR build (single-pass bucket scatter) as R9.
// ---------------------------------------------------------------------------

#define NBK 160            // max buckets: ceil(80000/512)=157 <= 160
#define HB  256            // edge-pass blocks in pA
#define CAP 9216           // per-bucket slot capacity (mean 8192, +11 sigma)

typedef __attribute__((ext_vector_type(8))) short bf16x8;
typedef __attribute__((ext_vector_type(4))) float f32x4;

__device__ __forceinline__ float bflo(unsigned u) { return __uint_as_float(u << 16); }
__device__ __forceinline__ float bfhi(unsigned u) { return __uint_as_float(u & 0xffff0000u); }
__device__ __forceinline__ float bf1(unsigned short u) { return __uint_as_float((unsigned)u << 16); }
__device__ __forceinline__ unsigned short f2bf(float f) {   // RNE
    unsigned u = __float_as_uint(f);
    return (unsigned short)((u + 0x7fff + ((u >> 16) & 1)) >> 16);
}

// --- pA: single-pass bucket scatter (blocks < HB) + graph bounds (rest) ----
__global__ __launch_bounds__(256) void pA_scatter(
    const int* __restrict__ src, const int* __restrict__ dst,
    int* __restrict__ curD, int* __restrict__ curS,       // NBK cursors each, pre-zeroed
    int* __restrict__ pack, unsigned short* __restrict__ sloc,
    const int* __restrict__ gids, int* __restrict__ goffs,
    int E, int NB, int N, int G)
{
    if (blockIdx.x >= HB) {                  // fused bounds_kernel
        int i = (blockIdx.x - HB) * 256 + threadIdx.x;
        if (i >= N) return;
        int b = gids[i];
        if (i == 0) {
            for (int g = 0; g <= b; g++) goffs[g] = 0;
        } else {
            int a = gids[i - 1];
            for (int g = a + 1; g <= b; g++) goffs[g] = i;
        }
        if (i == N - 1) {
            for (int g = b + 1; g <= G; g++) goffs[g] = N;
        }
        return;
    }
    __shared__ int hd[NBK], hs[NBK];
    int t = threadIdx.x;
    for (int i = t; i < NB; i += 256) { hd[i] = 0; hs[i] = 0; }
    __syncthreads();
    int chunk = (E + HB - 1) / HB;
    int s0 = blockIdx.x * chunk, s1 = min(E, s0 + chunk);
    for (int i = s0 + t; i < s1; i += 256) {
        atomicAdd(&hd[dst[i] >> 9], 1);      // LDS atomic
        atomicAdd(&hs[src[i] >> 9], 1);      // LDS atomic
    }
    __syncthreads();
    for (int b = t; b < NB; b += 256) {      // reserve global slots
        int cd = hd[b], cs = hs[b];
        hd[b] = cd ? atomicAdd(&curD[b], cd) : 0;   // device atomic, 1/bucket
        hs[b] = cs ? atomicAdd(&curS[b], cs) : 0;
    }
    __syncthreads();
    for (int i = s0 + t; i < s1; i += 256) { // chunk re-read is L2-hot
        int s = src[i], d = dst[i];
        int bd = d >> 9, bs = s >> 9;
        int pd = atomicAdd(&hd[bd], 1);      // LDS atomic
        int ps = atomicAdd(&hs[bs], 1);      // LDS atomic
        if (pd < CAP) pack[(size_t)bd * CAP + pd] = ((d & 511) << 17) | s;
        if (ps < CAP) sloc[(size_t)bs * CAP + ps] = (unsigned short)(s & 511);
    }
}

// --- p5: dst mode -> CSR (row_offs, col=full word, ndst); src -> nsrc+xs ---
__global__ __launch_bounds__(256) void p5_build(
    const int* __restrict__ pack, const unsigned short* __restrict__ sloc,
    const int* __restrict__ curD, const int* __restrict__ curS,
    int* __restrict__ col, int* __restrict__ row_offs,
    float* __restrict__ nsrc, float* __restrict__ ndst,
    const float* __restrict__ h, unsigned short* __restrict__ xs,
    int N, int NB)
{
    __shared__ int hist[512];
    __shared__ float nsl[512];
    __shared__ int wt[4];
    int t = threadIdx.x;
    bool dmode = blockIdx.x < NB;
    int b = dmode ? blockIdx.x : blockIdx.x - NB;
    int n0 = b << 9, n1 = min(N, n0 + 512);
    hist[t] = 0; hist[t + 256] = 0;
    __syncthreads();
    int e0 = b * CAP;
    int tot = min(dmode ? curD[b] : curS[b], CAP);
    int e1 = e0 + tot;
    if (!dmode) {
        for (int i = e0 + t; i < e1; i += 256)
            atomicAdd(&hist[sloc[i]], 1);            // LDS atomic
        __syncthreads();
        for (int n = n0 + t; n < n1; n += 256) {
            float s = rsqrtf((float)max(hist[n - n0], 1));
            nsrc[n] = s;
            nsl[n - n0] = s;
        }
        __syncthreads();
        int cnt = n1 - n0;
        const float2* h2p = (const float2*)h;
        ushort2* xp = (ushort2*)xs;
        for (int i = t; i < cnt * 32; i += 256) {
            int node = i >> 5;
            float s = nsl[node];
            float2 v = h2p[(size_t)(n0 + node) * 32 + (i & 31)];
            ushort2 o;
            o.x = f2bf(v.x * s);
            o.y = f2bf(v.y * s);
            xp[(size_t)(n0 + node) * 32 + (i & 31)] = o;
        }
        return;
    }
    for (int i = e0 + t; i < e1; i += 256)
        atomicAdd(&hist[pack[i] >> 17], 1);          // LDS atomic
    __syncthreads();
    int c0 = hist[2 * t], c1 = hist[2 * t + 1];
    int v = c0 + c1;
    int lane = t & 63, w = t >> 6;
    int x = v;
    #pragma unroll
    for (int off = 1; off < 64; off <<= 1) {
        int y = __shfl_up(x, off);
        if (lane >= off) x += y;
    }
    if (lane == 63) wt[w] = x;
    __syncthreads();
    int bw = 0;
    for (int i = 0; i < w; i++) bw += wt[i];
    int excl = x - v + bw;
    int n = n0 + 2 * t;
    if (n < n1) {
        row_offs[n] = e0 + excl;
        ndst[n] = rsqrtf((float)max(c0, 1));
    }
    if (n + 1 < n1) {
        row_offs[n + 1] = e0 + excl + c0;
        ndst[n + 1] = rsqrtf((float)max(c1, 1));
    }
    hist[2 * t] = excl;
    hist[2 * t + 1] = excl + c0;
    __syncthreads();
    for (int i = e0 + t; i < e1; i += 256) {
        int wd = pack[i];
        int pos = atomicAdd(&hist[wd >> 17], 1);     // LDS atomic
        col[e0 + pos] = wd;                          // keep full word
    }
}

// --- fused layer: edge-parallel LDS-atomic agg + MFMA + epilogue -----------
// block = 64-node tile (edges contiguous in col). sub=tid>>3 in 0..31 = edge
// slot, li=tid&7 = 16B feat chunk. acc[64][65] fp32, stride 65 spreads banks.
__global__ __launch_bounds__(256) void layer_kernel(
    const unsigned short* __restrict__ x,    // gather table, N x 64 bf16
    const int* __restrict__ col, const int* __restrict__ row_offs,
    const int* __restrict__ curD,
    const float* __restrict__ W, const float* __restrict__ b,
    const float* __restrict__ ndst, const float* __restrict__ nsrc,
    unsigned short* __restrict__ y,          // N x 64 bf16 out
    int N, int scale_out)
{
    __shared__ float acc[64 * 65];
    int t = threadIdx.x;
    int sub = t >> 3, li = t & 7;
    int lane = t & 63, w = t >> 6;
    int c16 = lane & 15, quad = lane >> 4;
    const uint4* x4 = (const uint4*)x;

    // B fragments + bias (W fp32 -> bf16) -- overlaps with LDS zeroing
    bf16x8 bfrag[4][2];
    #pragma unroll
    for (int nt = 0; nt < 4; nt++)
        #pragma unroll
        for (int ks = 0; ks < 2; ks++)
            #pragma unroll
            for (int j = 0; j < 8; j++)
                bfrag[nt][ks][j] =
                    (short)f2bf(W[(ks * 32 + quad * 8 + j) * 64 + nt * 16 + c16]);
    float bias[4];
    #pragma unroll
    for (int nt = 0; nt < 4; nt++) bias[nt] = b[nt * 16 + c16];

    for (int i = t; i < 64 * 65; i += 256) acc[i] = 0.f;

    int n0 = blockIdx.x * 64;
    int bkt = n0 >> 9;
    int off = n0 & 511;
    int e_start = row_offs[n0];
    int nend = n0 + 64;
    int e_end;
    if (nend >= N || (nend & 511) == 0) e_end = bkt * CAP + min(curD[bkt], CAP);
    else e_end = row_offs[nend];
    __syncthreads();

    for (int e = e_start + sub; e < e_end; e += 32) {
        int wd = col[e];                      // 8 li-threads share -> broadcast
        int dL = (wd >> 17) - off;
        int s  = wd & 0x1FFFF;
        uint4 v = x4[(size_t)s * 8 + li];
        float* a = &acc[dL * 65 + li * 8];
        atomicAdd(a + 0, bflo(v.x));
        atomicAdd(a + 1, bfhi(v.x));
        atomicAdd(a + 2, bflo(v.y));
        atomicAdd(a + 3, bfhi(v.y));
        atomicAdd(a + 4, bflo(v.z));
        atomicAdd(a + 5, bfhi(v.z));
        atomicAdd(a + 6, bflo(v.w));
        atomicAdd(a + 7, bfhi(v.w));
    }
    __syncthreads();

    // MFMA: wave w owns rows w*16..w*16+15. A frag from LDS sums (cvt bf16).
    int row = w * 16 + c16;
    bf16x8 a0, a1;
    #pragma unroll
    for (int j = 0; j < 8; j++) {
        a0[j] = (short)f2bf(acc[row * 65 + quad * 8 + j]);
        a1[j] = (short)f2bf(acc[row * 65 + 32 + quad * 8 + j]);
    }
    float nd[4], ns[4];
    #pragma unroll
    for (int rr = 0; rr < 4; rr++) {
        int m = min(n0 + w * 16 + quad * 4 + rr, N - 1);
        nd[rr] = ndst[m];
        ns[rr] = scale_out ? nsrc[m] : 1.f;
    }
    #pragma unroll
    for (int nt = 0; nt < 4; nt++) {
        f32x4 d = {0.f, 0.f, 0.f, 0.f};
        d = __builtin_amdgcn_mfma_f32_16x16x32_bf16(a0, bfrag[nt][0], d, 0, 0, 0);
        d = __builtin_amdgcn_mfma_f32_16x16x32_bf16(a1, bfrag[nt][1], d, 0, 0, 0);
        #pragma unroll
        for (int rr = 0; rr < 4; rr++) {
            int m = n0 + w * 16 + quad * 4 + rr;
            if (m < N)
                y[(size_t)m * 64 + nt * 16 + c16] =
                    f2bf(fmaxf(nd[rr] * d[rr] + bias[nt], 0.f) * ns[rr]);
        }
    }
}

// --- per-graph mean pool + 64x5 classifier (block per graph) ---------------
__global__ __launch_bounds__(256) void pool_kernel(
    const unsigned short* __restrict__ h2, const int* __restrict__ goffs,
    const float* __restrict__ Wc, const float* __restrict__ bc,
    float* __restrict__ out)
{
    int g = blockIdx.x;
    int lane = threadIdx.x & 63;
    int w = threadIdx.x >> 6;
    int s = goffs[g], e = goffs[g + 1];
    float acc = 0.f;
    for (int i = s + w; i < e; i += 4) acc += bf1(h2[i * 64 + lane]);
    __shared__ float red[4][64];
    red[w][lane] = acc;
    __syncthreads();
    if (w == 0) {
        float tot = red[0][lane] + red[1][lane] + red[2][lane] + red[3][lane];
        float mean = tot / (float)max(e - s, 1);
        float wc[5];
        #pragma unroll
        for (int c = 0; c < 5; c++) wc[c] = Wc[lane * 5 + c];
        #pragma unroll
        for (int c = 0; c < 5; c++) {
            float p = mean * wc[c];
            #pragma unroll
            for (int off = 32; off; off >>= 1) p += __shfl_down(p, off);
            if (lane == 0) out[g * 5 + c] = p + bc[c];
        }
    }
}

extern "C" void kernel_launch(void* const* d_in, const int* in_sizes, int n_in,
                              void* d_out, int out_size, void* d_ws, size_t ws_size,
                              hipStream_t stream)
{
    const float* h    = (const float*)d_in[0];
    const int*   src  = (const int*)d_in[1];
    const int*   dst  = (const int*)d_in[2];
    const int*   gids = (const int*)d_in[3];
    const float* W1   = (const float*)d_in[4];
    const float* b1   = (const float*)d_in[5];
    const float* W2   = (const float*)d_in[6];
    const float* b2   = (const float*)d_in[7];
    const float* Wc   = (const float*)d_in[8];
    const float* bc   = (const float*)d_in[9];
    float* out = (float*)d_out;

    const int N = in_sizes[0] / 64;
    const int E = in_sizes[1];
    const int G = out_size / 5;
    const int NB = (N + 511) >> 9;
    const int NBB = (N + 255) / 256;        // bounds blocks

    auto align = [](size_t x) { return (x + 255) & ~(size_t)255; };
    char* p = (char*)d_ws;
    int* curD    = (int*)p;            p += align((size_t)2 * NBK * 4);
    int* curS    = curD + NBK;
    int* row_offs= (int*)p;            p += align((size_t)N * 4);
    float* nsrc  = (float*)p;          p += align((size_t)N * 4);
    float* ndst  = (float*)p;          p += align((size_t)N * 4);
    int* goffs   = (int*)p;            p += align((size_t)(G + 1) * 4);
    int* pack    = (int*)p;            p += align((size_t)NBK * CAP * 4);
    unsigned short* sloc = (unsigned short*)p; p += align((size_t)NBK * CAP * 2);
    int* col     = (int*)p;            p += align((size_t)NBK * CAP * 4);
    unsigned short* xs  = (unsigned short*)p; p += align((size_t)N * 64 * 2);
    unsigned short* h1s = (unsigned short*)p; p += align((size_t)N * 64 * 2);
    unsigned short* h2  = xs;   // alias: xs dead after layer1

    hipMemsetAsync(curD, 0, (size_t)2 * NBK * 4, stream);

    pA_scatter<<<HB + NBB, 256, 0, stream>>>(src, dst, curD, curS, pack, sloc,
                                             gids, goffs, E, NB, N, G);
    p5_build<<<2 * NB, 256, 0, stream>>>(pack, sloc, curD, curS, col,
                                         row_offs, nsrc, ndst, h, xs, N, NB);

    layer_kernel<<<(N + 63) / 64, 256, 0, stream>>>(
        xs, col, row_offs, curD, W1, b1, ndst, nsrc, h1s, N, 1);
    layer_kernel<<<(N + 63) / 64, 256, 0, stream>>>(
        h1s, col, row_offs, curD, W2, b2, ndst, nsrc, h2, N, 0);

    pool_kernel<<<G, 256, 0, stream>>>(h2, goffs, Wc, bc, out);
}

// Round 11
// 223.897 us; speedup vs baseline: 4.5506x; 4.5506x over previous
//
#include <hip/hip_runtime.h>
#include <hip/hip_bf16.h>

// ---------------------------------------------------------------------------
// 2-layer GraphConv (DGL norm='both') + mean_nodes pool + linear classifier.
// N=80000, E=1.28M, D=H=64, C=5, G=512.
// R10->R11: HARD REVERT of R10's edge-parallel LDS-atomic layer (439us/layer:
// col is dst-sorted, deg~16 => ~16 consecutive edges share a dst row, so
// 16 subs x 8 lanes hammered the same 8 LDS addresses -> same-address atomic
// serialization, SQ_LDS_BANK_CONFLICT 0->160k). Back to R9 structure
// (wave-per-node agg + separate MFMA gemm). New, low-risk only:
// (a) pA edge reads int4-vectorized (4x fewer load instrs on the 2x20MB
//     edge streams, both passes);
// (b) agg grid 2048->4096 blocks (2x resident waves -> more independent
//     per-node latency chains in flight).
// ---------------------------------------------------------------------------

#define NBK 160            // max buckets: ceil(80000/512)=157 <= 160
#define HB  256            // edge-pass blocks in pA
#define CAP 9216           // per-bucket slot capacity (mean 8192, +11 sigma)

typedef __attribute__((ext_vector_type(8))) short bf16x8;
typedef __attribute__((ext_vector_type(4))) float f32x4;

__device__ __forceinline__ float bflo(unsigned u) { return __uint_as_float(u << 16); }
__device__ __forceinline__ float bfhi(unsigned u) { return __uint_as_float(u & 0xffff0000u); }
__device__ __forceinline__ float bf1(unsigned short u) { return __uint_as_float((unsigned)u << 16); }
__device__ __forceinline__ unsigned short f2bf(float f) {   // RNE
    unsigned u = __float_as_uint(f);
    return (unsigned short)((u + 0x7fff + ((u >> 16) & 1)) >> 16);
}
__device__ __forceinline__ unsigned packbf(float lo, float hi) {
    return (unsigned)f2bf(lo) | ((unsigned)f2bf(hi) << 16);
}

// --- pA: single-pass bucket scatter (blocks < HB) + graph bounds (rest) ----
__global__ __launch_bounds__(256) void pA_scatter(
    const int* __restrict__ src, const int* __restrict__ dst,
    int* __restrict__ curD, int* __restrict__ curS,       // NBK cursors each, pre-zeroed
    int* __restrict__ pack, unsigned short* __restrict__ sloc,
    const int* __restrict__ gids, int* __restrict__ goffs,
    int E, int NB, int N, int G)
{
    if (blockIdx.x >= HB) {                  // fused bounds_kernel
        int i = (blockIdx.x - HB) * 256 + threadIdx.x;
        if (i >= N) return;
        int b = gids[i];
        if (i == 0) {
            for (int g = 0; g <= b; g++) goffs[g] = 0;
        } else {
            int a = gids[i - 1];
            for (int g = a + 1; g <= b; g++) goffs[g] = i;
        }
        if (i == N - 1) {
            for (int g = b + 1; g <= G; g++) goffs[g] = N;
        }
        return;
    }
    __shared__ int hd[NBK], hs[NBK];
    int t = threadIdx.x;
    for (int i = t; i < NB; i += 256) { hd[i] = 0; hs[i] = 0; }
    __syncthreads();
    int chunk = (E + HB - 1) / HB;
    int s0 = blockIdx.x * chunk, s1 = min(E, s0 + chunk);
    // vectorized histogram pass
    int q0 = s0 >> 2, q1 = s1 >> 2;          // s0 is 4-aligned (chunk%4==0)
    const int4* s4 = (const int4*)src;
    const int4* d4 = (const int4*)dst;
    for (int q = q0 + t; q < q1; q += 256) {
        int4 d = d4[q];
        int4 s = s4[q];
        atomicAdd(&hd[d.x >> 9], 1); atomicAdd(&hd[d.y >> 9], 1);
        atomicAdd(&hd[d.z >> 9], 1); atomicAdd(&hd[d.w >> 9], 1);
        atomicAdd(&hs[s.x >> 9], 1); atomicAdd(&hs[s.y >> 9], 1);
        atomicAdd(&hs[s.z >> 9], 1); atomicAdd(&hs[s.w >> 9], 1);
    }
    for (int i = (q1 << 2) + t; i < s1; i += 256) {   // tail
        atomicAdd(&hd[dst[i] >> 9], 1);
        atomicAdd(&hs[src[i] >> 9], 1);
    }
    __syncthreads();
    for (int b = t; b < NB; b += 256) {      // reserve global slots
        int cd = hd[b], cs = hs[b];
        hd[b] = cd ? atomicAdd(&curD[b], cd) : 0;   // device atomic, 1/bucket
        hs[b] = cs ? atomicAdd(&curS[b], cs) : 0;
    }
    __syncthreads();
    // vectorized scatter pass (chunk re-read is L2-hot)
    for (int q = q0 + t; q < q1; q += 256) {
        int4 d = d4[q];
        int4 s = s4[q];
        #pragma unroll
        for (int j = 0; j < 4; j++) {
            int ss = j == 0 ? s.x : j == 1 ? s.y : j == 2 ? s.z : s.w;
            int dd = j == 0 ? d.x : j == 1 ? d.y : j == 2 ? d.z : d.w;
            int bd = dd >> 9, bs = ss >> 9;
            int pd = atomicAdd(&hd[bd], 1);  // LDS atomic
            int ps = atomicAdd(&hs[bs], 1);  // LDS atomic
            if (pd < CAP) pack[(size_t)bd * CAP + pd] = ((dd & 511) << 17) | ss;
            if (ps < CAP) sloc[(size_t)bs * CAP + ps] = (unsigned short)(ss & 511);
        }
    }
    for (int i = (q1 << 2) + t; i < s1; i += 256) {   // tail
        int s = src[i], d = dst[i];
        int bd = d >> 9, bs = s >> 9;
        int pd = atomicAdd(&hd[bd], 1);
        int ps = atomicAdd(&hs[bs], 1);
        if (pd < CAP) pack[(size_t)bd * CAP + pd] = ((d & 511) << 17) | s;
        if (ps < CAP) sloc[(size_t)bs * CAP + ps] = (unsigned short)(s & 511);
    }
}

// --- p5: dst mode -> CSR (row_offs,deg,col,ndst); src mode -> nsrc+prescale -
__global__ __launch_bounds__(256) void p5_build(
    const int* __restrict__ pack, const unsigned short* __restrict__ sloc,
    const int* __restrict__ curD, const int* __restrict__ curS,
    int* __restrict__ col, int* __restrict__ row_offs, int* __restrict__ deg,
    float* __restrict__ nsrc, float* __restrict__ ndst,
    const float* __restrict__ h, unsigned short* __restrict__ xs,
    int N, int NB)
{
    __shared__ int hist[512];
    __shared__ float nsl[512];
    __shared__ int wt[4];
    int t = threadIdx.x;
    bool dmode = blockIdx.x < NB;
    int b = dmode ? blockIdx.x : blockIdx.x - NB;
    int n0 = b << 9, n1 = min(N, n0 + 512);
    hist[t] = 0; hist[t + 256] = 0;
    __syncthreads();
    int e0 = b * CAP;
    int tot = min(dmode ? curD[b] : curS[b], CAP);
    int e1 = e0 + tot;
    if (!dmode) {
        for (int i = e0 + t; i < e1; i += 256)
            atomicAdd(&hist[sloc[i]], 1);            // LDS atomic
        __syncthreads();
        for (int n = n0 + t; n < n1; n += 256) {
            float s = rsqrtf((float)max(hist[n - n0], 1));
            nsrc[n] = s;
            nsl[n - n0] = s;
        }
        __syncthreads();
        int cnt = n1 - n0;
        const float2* h2p = (const float2*)h;
        ushort2* xp = (ushort2*)xs;
        for (int i = t; i < cnt * 32; i += 256) {
            int node = i >> 5;
            float s = nsl[node];
            float2 v = h2p[(size_t)(n0 + node) * 32 + (i & 31)];
            ushort2 o;
            o.x = f2bf(v.x * s);
            o.y = f2bf(v.y * s);
            xp[(size_t)(n0 + node) * 32 + (i & 31)] = o;
        }
        return;
    }
    for (int i = e0 + t; i < e1; i += 256)
        atomicAdd(&hist[pack[i] >> 17], 1);          // LDS atomic
    __syncthreads();
    int c0 = hist[2 * t], c1 = hist[2 * t + 1];
    int v = c0 + c1;
    int lane = t & 63, w = t >> 6;
    int x = v;
    #pragma unroll
    for (int off = 1; off < 64; off <<= 1) {
        int y = __shfl_up(x, off);
        if (lane >= off) x += y;
    }
    if (lane == 63) wt[w] = x;
    __syncthreads();
    int bw = 0;
    for (int i = 0; i < w; i++) bw += wt[i];
    int excl = x - v + bw;
    int n = n0 + 2 * t;
    if (n < n1) {
        row_offs[n] = e0 + excl;
        deg[n] = c0;
        ndst[n] = rsqrtf((float)max(c0, 1));
    }
    if (n + 1 < n1) {
        row_offs[n + 1] = e0 + excl + c0;
        deg[n + 1] = c1;
        ndst[n + 1] = rsqrtf((float)max(c1, 1));
    }
    hist[2 * t] = excl;
    hist[2 * t + 1] = excl + c0;
    __syncthreads();
    for (int i = e0 + t; i < e1; i += 256) {
        int wd = pack[i];
        int pos = atomicAdd(&hist[wd >> 17], 1);     // LDS atomic
        col[e0 + pos] = wd & 0x1FFFF;
    }
}

// --- pure gather-sum with next-node prefetch -------------------------------
__global__ __launch_bounds__(256) void agg_kernel(
    const unsigned short* __restrict__ z, unsigned short* __restrict__ y,
    const int* __restrict__ col, const int* __restrict__ row_offs,
    const int* __restrict__ deg, int N)
{
    int lane = threadIdx.x & 63;
    int sub  = lane >> 3;
    int li   = lane & 7;
    const uint4* x4 = (const uint4*)z;

    int wid = (blockIdx.x * 256 + threadIdx.x) >> 6;
    int nw  = (gridDim.x * 256) >> 6;

    int ro = 0, cnt = 0, idx = 0;
    if (wid < N) {
        ro = row_offs[wid];
        cnt = deg[wid];
        if (lane < min(cnt, 64)) idx = col[ro + lane];
    }
    for (int node = wid; node < N; node += nw) {
        int nnode = node + nw;
        int nro = 0, ncnt = 0;
        if (nnode < N) { nro = row_offs[nnode]; ncnt = deg[nnode]; }  // prefetch

        float a0=0.f,a1=0.f,a2=0.f,a3=0.f,a4=0.f,a5=0.f,a6=0.f,a7=0.f;
        int cc = 0;
        int cidx = idx;
        while (cc < cnt) {
            int m = min(cnt - cc, 64);
            for (int i = 0; i < m; i += 32) {
                int e1 = i + sub, e2 = i + 8 + sub, e3 = i + 16 + sub, e4 = i + 24 + sub;
                int s1 = __shfl(cidx, min(e1, m - 1));
                int s2 = __shfl(cidx, min(e2, m - 1));
                int s3 = __shfl(cidx, min(e3, m - 1));
                int s4 = __shfl(cidx, min(e4, m - 1));
                uint4 v1 = make_uint4(0u,0u,0u,0u), v2 = v1, v3 = v1, v4 = v1;
                if (e1 < m) v1 = x4[(size_t)s1 * 8 + li];
                if (e2 < m) v2 = x4[(size_t)s2 * 8 + li];
                if (e3 < m) v3 = x4[(size_t)s3 * 8 + li];
                if (e4 < m) v4 = x4[(size_t)s4 * 8 + li];
                a0 += bflo(v1.x); a1 += bfhi(v1.x);
                a2 += bflo(v1.y); a3 += bfhi(v1.y);
                a4 += bflo(v1.z); a5 += bfhi(v1.z);
                a6 += bflo(v1.w); a7 += bfhi(v1.w);
                a0 += bflo(v2.x); a1 += bfhi(v2.x);
                a2 += bflo(v2.y); a3 += bfhi(v2.y);
                a4 += bflo(v2.z); a5 += bfhi(v2.z);
                a6 += bflo(v2.w); a7 += bfhi(v2.w);
                a0 += bflo(v3.x); a1 += bfhi(v3.x);
                a2 += bflo(v3.y); a3 += bfhi(v3.y);
                a4 += bflo(v3.z); a5 += bfhi(v3.z);
                a6 += bflo(v3.w); a7 += bfhi(v3.w);
                a0 += bflo(v4.x); a1 += bfhi(v4.x);
                a2 += bflo(v4.y); a3 += bfhi(v4.y);
                a4 += bflo(v4.z); a5 += bfhi(v4.z);
                a6 += bflo(v4.w); a7 += bfhi(v4.w);
            }
            cc += 64;
            if (cc < cnt) cidx = (lane < min(cnt - cc, 64)) ? col[ro + cc + lane] : 0;
        }
        // prefetch next node's col during the reduce
        idx = 0;
        if (nnode < N && lane < min(ncnt, 64)) idx = col[nro + lane];

        #pragma unroll
        for (int off = 8; off <= 32; off <<= 1) {
            a0 += __shfl_xor(a0, off); a1 += __shfl_xor(a1, off);
            a2 += __shfl_xor(a2, off); a3 += __shfl_xor(a3, off);
            a4 += __shfl_xor(a4, off); a5 += __shfl_xor(a5, off);
            a6 += __shfl_xor(a6, off); a7 += __shfl_xor(a7, off);
        }
        if (sub == 0) {                       // 8 lanes store the 128B row
            uint4 o;
            o.x = packbf(a0, a1);
            o.y = packbf(a2, a3);
            o.z = packbf(a4, a5);
            o.w = packbf(a6, a7);
            ((uint4*)y)[(size_t)node * 8 + li] = o;
        }
        ro = nro; cnt = ncnt;
    }
}

// --- GEMM + epilogue: Z[m] = relu(ndst[m]*(S[m]@W) + b) [* nsrc[m]] --------
__global__ __launch_bounds__(256) void gemm_kernel(
    const unsigned short* __restrict__ A, const float* __restrict__ W,
    const float* __restrict__ b, const float* __restrict__ ndst,
    const float* __restrict__ nsrc, unsigned short* __restrict__ Z,
    int M, int scale_out)
{
    int t = threadIdx.x, lane = t & 63, w = t >> 6;
    int col = lane & 15, quad = lane >> 4;
    bf16x8 bfrag[4][2];
    #pragma unroll
    for (int nt = 0; nt < 4; nt++)
        #pragma unroll
        for (int ks = 0; ks < 2; ks++)
            #pragma unroll
            for (int j = 0; j < 8; j++)
                bfrag[nt][ks][j] =
                    (short)f2bf(W[(ks * 32 + quad * 8 + j) * 64 + nt * 16 + col]);
    float bias[4];
    #pragma unroll
    for (int nt = 0; nt < 4; nt++) bias[nt] = b[nt * 16 + col];

    int mbase = blockIdx.x * 64 + w * 16;
    if (mbase >= M) return;
    int row = min(mbase + col, M - 1);
    const uint4* a4 = (const uint4*)A;
    union { uint4 u; bf16x8 v; } a0, a1;
    a0.u = a4[(size_t)row * 8 + quad];
    a1.u = a4[(size_t)row * 8 + 4 + quad];

    float nd[4], ns[4];
    #pragma unroll
    for (int r = 0; r < 4; r++) {
        int m = min(mbase + quad * 4 + r, M - 1);
        nd[r] = ndst[m];
        ns[r] = scale_out ? nsrc[m] : 1.f;
    }

    #pragma unroll
    for (int nt = 0; nt < 4; nt++) {
        f32x4 acc = {0.f, 0.f, 0.f, 0.f};
        acc = __builtin_amdgcn_mfma_f32_16x16x32_bf16(a0.v, bfrag[nt][0], acc, 0, 0, 0);
        acc = __builtin_amdgcn_mfma_f32_16x16x32_bf16(a1.v, bfrag[nt][1], acc, 0, 0, 0);
        #pragma unroll
        for (int r = 0; r < 4; r++) {
            int m = mbase + quad * 4 + r;
            if (m < M)
                Z[(size_t)m * 64 + nt * 16 + col] =
                    f2bf(fmaxf(nd[r] * acc[r] + bias[nt], 0.f) * ns[r]);
        }
    }
}

// --- per-graph mean pool + 64x5 classifier (block per graph) ---------------
__global__ __launch_bounds__(256) void pool_kernel(
    const unsigned short* __restrict__ h2, const int* __restrict__ goffs,
    const float* __restrict__ Wc, const float* __restrict__ bc,
    float* __restrict__ out)
{
    int g = blockIdx.x;
    int lane = threadIdx.x & 63;
    int w = threadIdx.x >> 6;
    int s = goffs[g], e = goffs[g + 1];
    float acc = 0.f;
    for (int i = s + w; i < e; i += 4) acc += bf1(h2[i * 64 + lane]);
    __shared__ float red[4][64];
    red[w][lane] = acc;
    __syncthreads();
    if (w == 0) {
        float tot = red[0][lane] + red[1][lane] + red[2][lane] + red[3][lane];
        float mean = tot / (float)max(e - s, 1);
        float wc[5];
        #pragma unroll
        for (int c = 0; c < 5; c++) wc[c] = Wc[lane * 5 + c];
        #pragma unroll
        for (int c = 0; c < 5; c++) {
            float p = mean * wc[c];
            #pragma unroll
            for (int off = 32; off; off >>= 1) p += __shfl_down(p, off);
            if (lane == 0) out[g * 5 + c] = p + bc[c];
        }
    }
}

extern "C" void kernel_launch(void* const* d_in, const int* in_sizes, int n_in,
                              void* d_out, int out_size, void* d_ws, size_t ws_size,
                              hipStream_t stream)
{
    const float* h    = (const float*)d_in[0];
    const int*   src  = (const int*)d_in[1];
    const int*   dst  = (const int*)d_in[2];
    const int*   gids = (const int*)d_in[3];
    const float* W1   = (const float*)d_in[4];
    const float* b1   = (const float*)d_in[5];
    const float* W2   = (const float*)d_in[6];
    const float* b2   = (const float*)d_in[7];
    const float* Wc   = (const float*)d_in[8];
    const float* bc   = (const float*)d_in[9];
    float* out = (float*)d_out;

    const int N = in_sizes[0] / 64;
    const int E = in_sizes[1];
    const int G = out_size / 5;
    const int NB = (N + 511) >> 9;
    const int NBB = (N + 255) / 256;        // bounds blocks

    auto align = [](size_t x) { return (x + 255) & ~(size_t)255; };
    char* p = (char*)d_ws;
    int* curD    = (int*)p;            p += align((size_t)2 * NBK * 4);
    int* curS    = curD + NBK;
    int* row_offs= (int*)p;            p += align((size_t)N * 4);
    int* deg     = (int*)p;            p += align((size_t)N * 4);
    float* nsrc  = (float*)p;          p += align((size_t)N * 4);
    float* ndst  = (float*)p;          p += align((size_t)N * 4);
    int* goffs   = (int*)p;            p += align((size_t)(G + 1) * 4);
    int* pack    = (int*)p;            p += align((size_t)NBK * CAP * 4);
    unsigned short* sloc = (unsigned short*)p; p += align((size_t)NBK * CAP * 2);
    int* col     = (int*)p;            p += align((size_t)NBK * CAP * 4);
    unsigned short* xs  = (unsigned short*)p; p += align((size_t)N * 64 * 2);
    unsigned short* s1  = (unsigned short*)p; p += align((size_t)N * 64 * 2);
    unsigned short* h1s = (unsigned short*)p; p += align((size_t)N * 64 * 2);
    unsigned short* s2  = s1;   // alias: s1 dead after gemm1
    unsigned short* h2  = xs;   // alias: xs dead after agg1

    hipMemsetAsync(curD, 0, (size_t)2 * NBK * 4, stream);

    pA_scatter<<<HB + NBB, 256, 0, stream>>>(src, dst, curD, curS, pack, sloc,
                                             gids, goffs, E, NB, N, G);
    p5_build<<<2 * NB, 256, 0, stream>>>(pack, sloc, curD, curS, col,
                                         row_offs, deg, nsrc, ndst, h, xs, N, NB);

    agg_kernel<<<4096, 256, 0, stream>>>(xs, s1, col, row_offs, deg, N);
    gemm_kernel<<<(N + 63) / 64, 256, 0, stream>>>(s1, W1, b1, ndst, nsrc,
                                                   h1s, N, 1);
    agg_kernel<<<4096, 256, 0, stream>>>(h1s, s2, col, row_offs, deg, N);
    gemm_kernel<<<(N + 63) / 64, 256, 0, stream>>>(s2, W2, b2, ndst, nsrc,
                                                   h2, N, 0);

    pool_kernel<<<G, 256, 0, stream>>>(h2, goffs, Wc, bc, out);
}